// Round 3
// baseline (152.119 us; speedup 1.0000x reference)
//
#include <hip/hip_runtime.h>
#include <math.h>

#define BATCH 32
#define CH 3
#define HH 256
#define WW 256
#define PP 32
#define NPATCH 4

// ---------------- pool: pooled(b,c,8,8) = mean over 32x32 blocks -> feat[b,192]
__global__ __launch_bounds__(256) void pool_kernel(const float* __restrict__ x,
                                                   float* __restrict__ feat) {
  int wave = threadIdx.x >> 6;
  int lane = threadIdx.x & 63;
  int cell = blockIdx.x * 4 + wave;            // 0..6143 = b*192 + c*64 + i*8 + j
  int b = cell / 192;
  int rem = cell % 192;
  int c = rem >> 6;
  int ij = rem & 63;
  int i = ij >> 3, j = ij & 7;
  const float* base = x + ((size_t)(b * CH + c)) * HH * WW;
  int dr = lane >> 5, dc = lane & 31;
  int col = j * 32 + dc;
  float s = 0.f;
#pragma unroll
  for (int it = 0; it < 16; ++it) {
    int row = i * 32 + it * 2 + dr;
    s += base[row * WW + col];
  }
#pragma unroll
  for (int m = 32; m >= 1; m >>= 1) s += __shfl_xor(s, m, 64);
  if (lane == 0) feat[cell] = s * (1.f / 1024.f);
}

// ---------------- mlp
__global__ __launch_bounds__(128) void mlp_kernel(const float* __restrict__ feat,
                                                  const float* __restrict__ pw1,
                                                  const float* __restrict__ pb1,
                                                  const float* __restrict__ pw2,
                                                  const float* __restrict__ pb2,
                                                  int* __restrict__ posw) {
  int b = blockIdx.x;
  int t = threadIdx.x;
  __shared__ float fs[192];
  __shared__ float hs[128];
  for (int k = t; k < 192; k += 128) fs[k] = feat[b * 192 + k];
  __syncthreads();
  float a = pb1[t];
  for (int k = 0; k < 192; ++k) a = fmaf(fs[k], pw1[t * 192 + k], a);
  hs[t] = fmaxf(a, 0.f);
  __syncthreads();
  if (t < 8) {
    float a2 = pb2[t];
    for (int k = 0; k < 128; ++k) a2 = fmaf(hs[k], pw2[t * 128 + k], a2);
    float sgm = 1.f / (1.f + expf(-a2));
    posw[b * 8 + t] = (int)floorf(sgm * (float)(HH - PP));
  }
}

// ---------------- copy x -> out (vectorized)
__global__ __launch_bounds__(256) void copy_kernel(const float4* __restrict__ src,
                                                   float4* __restrict__ dst, int n4) {
  int i = blockIdx.x * 256 + threadIdx.x;
  if (i < n4) dst[i] = src[i];
}

// ---------------- patch: per (b,p,subtile) block: 32x4 output rows (8 subtiles)
// local frames (ROWS=4):
//   h2: rows rowbase-1 .. rowbase+4   (6)  x 34 cols = 204
//   h1: rows rowbase-2 .. rowbase+5   (8)  x 36 cols = 288
//   x : rows rowbase-3 .. rowbase+6   (10) x 38 cols = 380
__global__ __launch_bounds__(256) void patch_kernel(
    const float* __restrict__ x, const float* __restrict__ w1,
    const float* __restrict__ b1, const float* __restrict__ w2,
    const float* __restrict__ b2, const float* __restrict__ w3,
    const float* __restrict__ b3, const int* __restrict__ posw,
    float* __restrict__ out) {
  const int blk = blockIdx.x;
  const int s = blk & 7;
  const int p = (blk >> 3) & 3;
  const int b = blk >> 5;
  const int y0 = posw[b * 8 + p * 2 + 0];
  const int x0 = posw[b * 8 + p * 2 + 1];
  const int t = threadIdx.x;
  const int rowbase = s * 4;

  __shared__ float xs[3][10 * 38];   // 1140 f
  __shared__ float h1s[16][8 * 36];  // 4608 f (one 16-channel chunk)
  __shared__ float h2s[16][6 * 34];  // 3264 f
  // total 9012 f = 36 KB -> 4 blocks/CU

  // stage x window (zero-padded)
  for (int idx = t; idx < 3 * 10 * 38; idx += 256) {
    int c = idx / (10 * 38);
    int r = idx - c * (10 * 38);
    int ky = r / 38, kx = r - (r / 38) * 38;
    int gy = y0 + rowbase - 3 + ky, gx = x0 - 3 + kx;
    float v = 0.f;
    if ((unsigned)gy < 256u && (unsigned)gx < 256u)
      v = x[((size_t)(b * 3 + c) * 256 + gy) * 256 + gx];
    xs[c][ky * 38 + kx] = v;
  }

  // h2 position: one per thread (204 used, rest clamped & not written)
  const bool hvalid = t < 204;
  const int hidx = hvalid ? t : 203;
  const int iy = hidx / 34, ix = hidx - (hidx / 34) * 34;
  const bool inimg = ((unsigned)(y0 + rowbase - 1 + iy) < 256u) &&
                     ((unsigned)(x0 - 1 + ix) < 256u);

  // h1 slot0: idx=t (always < 288); slot1: idx=256+t for t<32
  const int jy0 = t / 36, jx0 = t - (t / 36) * 36;
  const bool in0 = ((unsigned)(y0 + rowbase - 2 + jy0) < 256u) &&
                   ((unsigned)(x0 - 2 + jx0) < 256u);
  const int i1 = 256 + t;  // only meaningful for t<32
  const int jy1 = i1 / 36, jx1 = i1 - (i1 / 36) * 36;
  const bool in1 = ((unsigned)(y0 + rowbase - 2 + jy1) < 256u) &&
                   ((unsigned)(x0 - 2 + jx1) < 256u);

  float acc[16];
#pragma unroll
  for (int c2 = 0; c2 < 16; ++c2) acc[c2] = 0.f;

  __syncthreads();

  for (int chunk = 0; chunk < 2; ++chunk) {
    // ---- h1 for this chunk's 16 channels
    {
      float xw[27];
#pragma unroll
      for (int c = 0; c < 3; ++c)
#pragma unroll
        for (int dy = 0; dy < 3; ++dy)
#pragma unroll
          for (int dx = 0; dx < 3; ++dx)
            xw[(c * 3 + dy) * 3 + dx] = xs[c][(jy0 + dy) * 38 + (jx0 + dx)];
#pragma unroll
      for (int cc = 0; cc < 16; ++cc) {
        int c1 = chunk * 16 + cc;
        float ssum = b1[c1];
#pragma unroll
        for (int k = 0; k < 27; ++k) ssum = fmaf(w1[c1 * 27 + k], xw[k], ssum);
        h1s[cc][t] = in0 ? fmaxf(ssum, 0.f) : 0.f;
      }
    }
    if (t < 32) {
      float xw[27];
#pragma unroll
      for (int c = 0; c < 3; ++c)
#pragma unroll
        for (int dy = 0; dy < 3; ++dy)
#pragma unroll
          for (int dx = 0; dx < 3; ++dx)
            xw[(c * 3 + dy) * 3 + dx] = xs[c][(jy1 + dy) * 38 + (jx1 + dx)];
#pragma unroll
      for (int cc = 0; cc < 16; ++cc) {
        int c1 = chunk * 16 + cc;
        float ssum = b1[c1];
#pragma unroll
        for (int k = 0; k < 27; ++k) ssum = fmaf(w1[c1 * 27 + k], xw[k], ssum);
        h1s[cc][i1] = in1 ? fmaxf(ssum, 0.f) : 0.f;
      }
    }
    __syncthreads();

    // ---- h2 accumulate over this chunk's 16 channels
#pragma unroll
    for (int cc = 0; cc < 16; ++cc) {
      int c1 = chunk * 16 + cc;
      float hw[9];
#pragma unroll
      for (int dy = 0; dy < 3; ++dy)
#pragma unroll
        for (int dx = 0; dx < 3; ++dx)
          hw[dy * 3 + dx] = h1s[cc][(iy + dy) * 36 + (ix + dx)];
#pragma unroll
      for (int c2 = 0; c2 < 16; ++c2) {
#pragma unroll
        for (int k = 0; k < 9; ++k)
          acc[c2] = fmaf(w2[(c2 * 32 + c1) * 9 + k], hw[k], acc[c2]);
      }
    }
    __syncthreads();
  }

  // write h2 (bias + relu; zero outside image)
  if (hvalid) {
#pragma unroll
    for (int c2 = 0; c2 < 16; ++c2) {
      float v = fmaxf(acc[c2] + b2[c2], 0.f);
      h2s[c2][hidx] = inimg ? v : 0.f;
    }
  }
  __syncthreads();

  // final conv (3 out ch) + tanh*0.1 + atomicAdd; 128 output pixels
  if (t < 128) {
    int oy = t >> 5, ox = t & 31;
    float a0 = b3[0], a1 = b3[1], a2 = b3[2];
#pragma unroll
    for (int c2 = 0; c2 < 16; ++c2) {
#pragma unroll
      for (int dy = 0; dy < 3; ++dy)
#pragma unroll
        for (int dx = 0; dx < 3; ++dx) {
          float h = h2s[c2][(oy + dy) * 34 + (ox + dx)];
          a0 = fmaf(w3[(0 * 16 + c2) * 9 + dy * 3 + dx], h, a0);
          a1 = fmaf(w3[(1 * 16 + c2) * 9 + dy * 3 + dx], h, a1);
          a2 = fmaf(w3[(2 * 16 + c2) * 9 + dy * 3 + dx], h, a2);
        }
    }
    int gy = y0 + rowbase + oy, gx = x0 + ox;
    atomicAdd(&out[((size_t)(b * 3 + 0) * 256 + gy) * 256 + gx], tanhf(a0) * 0.1f);
    atomicAdd(&out[((size_t)(b * 3 + 1) * 256 + gy) * 256 + gx], tanhf(a1) * 0.1f);
    atomicAdd(&out[((size_t)(b * 3 + 2) * 256 + gy) * 256 + gx], tanhf(a2) * 0.1f);
  }
}

extern "C" void kernel_launch(void* const* d_in, const int* in_sizes, int n_in,
                              void* d_out, int out_size, void* d_ws, size_t ws_size,
                              hipStream_t stream) {
  const float* x   = (const float*)d_in[0];
  const float* w1  = (const float*)d_in[1];
  const float* b1  = (const float*)d_in[2];
  const float* w2  = (const float*)d_in[3];
  const float* b2  = (const float*)d_in[4];
  const float* w3  = (const float*)d_in[5];
  const float* b3  = (const float*)d_in[6];
  const float* pw1 = (const float*)d_in[7];
  const float* pb1 = (const float*)d_in[8];
  const float* pw2 = (const float*)d_in[9];
  const float* pb2 = (const float*)d_in[10];
  float* out = (float*)d_out;

  float* feat = (float*)d_ws;                                  // 6144 floats
  int* posw = (int*)((char*)d_ws + 6144 * sizeof(float));      // 256 ints

  pool_kernel<<<1536, 256, 0, stream>>>(x, feat);
  mlp_kernel<<<BATCH, 128, 0, stream>>>(feat, pw1, pb1, pw2, pb2, posw);
  int n4 = (BATCH * CH * HH * WW) / 4;
  copy_kernel<<<(n4 + 255) / 256, 256, 0, stream>>>((const float4*)x, (float4*)out, n4);
  patch_kernel<<<BATCH * NPATCH * 8, 256, 0, stream>>>(x, w1, b1, w2, b2, w3, b3, posw, out);
}

// Round 4
// 67.744 us; speedup vs baseline: 2.2455x; 2.2455x over previous
//
#include <hip/hip_runtime.h>
#include <math.h>

#define BATCH 32
#define CH 3
#define HH 256
#define WW 256
#define PP 32
#define NPATCH 4

typedef __attribute__((ext_vector_type(8))) short short8;
typedef __attribute__((ext_vector_type(4))) float f32x4;

__device__ __forceinline__ unsigned short f2bf(float f) {
  union { float f; unsigned u; } cv;
  cv.f = f;
  unsigned u = cv.u;
  u += 0x7FFFu + ((u >> 16) & 1u);
  return (unsigned short)(u >> 16);
}

// ---------------- pool: pooled(b,c,8,8) = mean over 32x32 blocks -> feat[b,192]
__global__ __launch_bounds__(256) void pool_kernel(const float* __restrict__ x,
                                                   float* __restrict__ feat) {
  int wave = threadIdx.x >> 6;
  int lane = threadIdx.x & 63;
  int cell = blockIdx.x * 4 + wave;
  int b = cell / 192;
  int rem = cell % 192;
  int c = rem >> 6;
  int ij = rem & 63;
  int i = ij >> 3, j = ij & 7;
  const float* base = x + ((size_t)(b * CH + c)) * HH * WW;
  int dr = lane >> 5, dc = lane & 31;
  int col = j * 32 + dc;
  float s = 0.f;
#pragma unroll
  for (int it = 0; it < 16; ++it) {
    int row = i * 32 + it * 2 + dr;
    s += base[row * WW + col];
  }
#pragma unroll
  for (int m = 32; m >= 1; m >>= 1) s += __shfl_xor(s, m, 64);
  if (lane == 0) feat[cell] = s * (1.f / 1024.f);
}

// ---------------- mlp
__global__ __launch_bounds__(128) void mlp_kernel(const float* __restrict__ feat,
                                                  const float* __restrict__ pw1,
                                                  const float* __restrict__ pb1,
                                                  const float* __restrict__ pw2,
                                                  const float* __restrict__ pb2,
                                                  int* __restrict__ posw) {
  int b = blockIdx.x;
  int t = threadIdx.x;
  __shared__ float fs[192];
  __shared__ float hs[128];
  for (int k = t; k < 192; k += 128) fs[k] = feat[b * 192 + k];
  __syncthreads();
  float a = pb1[t];
  for (int k = 0; k < 192; ++k) a = fmaf(fs[k], pw1[t * 192 + k], a);
  hs[t] = fmaxf(a, 0.f);
  __syncthreads();
  if (t < 8) {
    float a2 = pb2[t];
    for (int k = 0; k < 128; ++k) a2 = fmaf(hs[k], pw2[t * 128 + k], a2);
    float sgm = 1.f / (1.f + expf(-a2));
    posw[b * 8 + t] = (int)floorf(sgm * (float)(HH - PP));
  }
}

// ---------------- copy x -> out (vectorized)
__global__ __launch_bounds__(256) void copy_kernel(const float4* __restrict__ src,
                                                   float4* __restrict__ dst, int n4) {
  int i = blockIdx.x * 256 + threadIdx.x;
  if (i < n4) dst[i] = src[i];
}

// ---------------- patch (MFMA): per (b,p,s) block, 32x4 output rows
// frames: out 4x32 @ (y0+rb, x0); h2 6x34 @ (-1,-1); h1 8x36 @ (-2,-2); x 10x38 @ (-3,-3)
__global__ __launch_bounds__(256) void patch_kernel(
    const float* __restrict__ x, const float* __restrict__ w1,
    const float* __restrict__ b1, const float* __restrict__ w2,
    const float* __restrict__ b2, const float* __restrict__ w3,
    const float* __restrict__ b3, const int* __restrict__ posw,
    float* __restrict__ out) {
  const int blk = blockIdx.x;
  const int s = blk & 7;
  const int p = (blk >> 3) & 3;
  const int b = blk >> 5;
  const int y0 = posw[b * 8 + p * 2 + 0];
  const int x0 = posw[b * 8 + p * 2 + 1];
  const int rb = s * 4;
  const int t = threadIdx.x;
  const int wv = t >> 6;
  const int lane = t & 63;
  const int lrow = lane & 15;   // MFMA A-row / B-col / D-col
  const int lgrp = lane >> 4;   // MFMA k-group; D-row = lgrp*4+reg

  __shared__ __align__(16) float xs[3][380];            // 4560 B
  __shared__ __align__(16) unsigned short h1ls[288 * 40]; // rows 80B: 32 bf16 + pad
  __shared__ __align__(16) unsigned short h2ls[208 * 16]; // rows 32B: 16 bf16

  // ---- stage x window (zero-padded, coalesced)
#pragma unroll
  for (int k = 0; k < 5; ++k) {
    int idx = t + 256 * k;
    if (idx < 1140) {
      int c = idx / 380;
      int r = idx - c * 380;
      int ky = r / 38, kx = r - (r / 38) * 38;
      int gy = y0 + rb - 3 + ky, gx = x0 - 3 + kx;
      float v = 0.f;
      if ((unsigned)gy < 256u && (unsigned)gx < 256u)
        v = x[((size_t)(b * 3 + c) * 256 + gy) * 256 + gx];
      xs[c][r] = v;
    }
  }
  __syncthreads();

  // ---- phase 1: h1 on VALU -> h1ls[pos][c1] bf16
  auto h1do = [&](int pos) {
    int jy = pos / 36, jx = pos - (pos / 36) * 36;
    bool inim = ((unsigned)(y0 + rb - 2 + jy) < 256u) &&
                ((unsigned)(x0 - 2 + jx) < 256u);
    float xw[27];
#pragma unroll
    for (int c = 0; c < 3; ++c)
#pragma unroll
      for (int dy = 0; dy < 3; ++dy)
#pragma unroll
        for (int dx = 0; dx < 3; ++dx)
          xw[c * 9 + dy * 3 + dx] = xs[c][(jy + dy) * 38 + (jx + dx)];
    unsigned short hv[32];
#pragma unroll
    for (int c1 = 0; c1 < 32; ++c1) {
      float ssum = b1[c1];
#pragma unroll
      for (int k = 0; k < 27; ++k) ssum = fmaf(w1[c1 * 27 + k], xw[k], ssum);
      hv[c1] = inim ? f2bf(fmaxf(ssum, 0.f)) : (unsigned short)0;
    }
#pragma unroll
    for (int q = 0; q < 4; ++q) {
      short8 v8;
#pragma unroll
      for (int j = 0; j < 8; ++j) v8[j] = (short)hv[q * 8 + j];
      *(short8*)&h1ls[pos * 40 + q * 8] = v8;
    }
  };
  h1do(t);
  if (t < 32) h1do(256 + t);

  // ---- B-frag preloads (consumed after barrier; latency hides under barrier)
  // h2 weights: k-step = tap; lane holds c2=lrow, c1=lgrp*8+j
  short8 b2f[9];
#pragma unroll
  for (int tap = 0; tap < 9; ++tap) {
#pragma unroll
    for (int j = 0; j < 8; ++j)
      b2f[tap][j] = (short)f2bf(w2[lrow * 288 + (lgrp * 8 + j) * 9 + tap]);
  }
  // h3 weights: k = tap*16 + c2 (K=144 pad 160); lane holds n=lrow
  short8 b3f[5];
#pragma unroll
  for (int kk = 0; kk < 5; ++kk) {
#pragma unroll
    for (int j = 0; j < 8; ++j) {
      int tap = 2 * kk + (lgrp >> 1);
      int c2 = (lgrp & 1) * 8 + j;
      float v = (lrow < 3 && tap < 9) ? w3[lrow * 144 + c2 * 9 + tap] : 0.f;
      b3f[kk][j] = (short)f2bf(v);
    }
  }
  float bias2 = b2[lrow];
  float bias3 = (lrow < 3) ? b3[lrow] : 0.f;

  __syncthreads();

  // ---- phase 2: h2 GEMM, M=208 (13 tiles), tiles mt = wv + 4*i
  f32x4 acc[4];
#pragma unroll
  for (int i = 0; i < 4; ++i) acc[i] = f32x4{0.f, 0.f, 0.f, 0.f};
#pragma unroll
  for (int i = 0; i < 4; ++i) {
    int mt = wv + 4 * i;
    if (mt < 13) {
      int pos = mt * 16 + lrow;
      int posc = pos < 204 ? pos : 203;
      int iy = posc / 34, ix = posc - (posc / 34) * 34;
      const unsigned short* abase = &h1ls[(iy * 36 + ix) * 40 + lgrp * 8];
      f32x4 c = f32x4{0.f, 0.f, 0.f, 0.f};
#pragma unroll
      for (int dy = 0; dy < 3; ++dy)
#pragma unroll
        for (int dx = 0; dx < 3; ++dx) {
          short8 a = *(const short8*)(abase + (dy * 36 + dx) * 40);
          c = __builtin_amdgcn_mfma_f32_16x16x32_bf16(a, b2f[dy * 3 + dx], c, 0, 0, 0);
        }
      acc[i] = c;
    }
  }
  // epilogue: D row=(lgrp*4+r), col=lrow  ->  h2ls[pos][c2]
#pragma unroll
  for (int i = 0; i < 4; ++i) {
    int mt = wv + 4 * i;
    if (mt < 13) {
#pragma unroll
      for (int r = 0; r < 4; ++r) {
        int pos = mt * 16 + lgrp * 4 + r;
        if (pos < 204) {
          int iy = pos / 34, ix = pos - (pos / 34) * 34;
          bool inim = ((unsigned)(y0 + rb - 1 + iy) < 256u) &&
                      ((unsigned)(x0 - 1 + ix) < 256u);
          float v = fmaxf(acc[i][r] + bias2, 0.f);
          h2ls[pos * 16 + lrow] = inim ? f2bf(v) : (unsigned short)0;
        }
      }
    }
  }
  __syncthreads();

  // ---- phase 3: h3 GEMM, M=128 (8 tiles), tiles mt = wv*2 + i
  f32x4 acc3[2];
#pragma unroll
  for (int i = 0; i < 2; ++i) {
    int mt = wv * 2 + i;
    int pix = mt * 16 + lrow;
    int oy = pix >> 5, ox = pix & 31;
    f32x4 c = f32x4{0.f, 0.f, 0.f, 0.f};
#pragma unroll
    for (int kk = 0; kk < 5; ++kk) {
      int tap = 2 * kk + (lgrp >> 1);
      short8 a = short8{0, 0, 0, 0, 0, 0, 0, 0};
      if (tap < 9) {
        int dy = (tap * 11) >> 5;
        int dx = tap - dy * 3;
        a = *(const short8*)&h2ls[((oy + dy) * 34 + (ox + dx)) * 16 + (lgrp & 1) * 8];
      }
      c = __builtin_amdgcn_mfma_f32_16x16x32_bf16(a, b3f[kk], c, 0, 0, 0);
    }
    acc3[i] = c;
  }
  // epilogue: tanh*0.1 + atomicAdd; D row=pixel, col=c3 (only 3 valid)
  if (lrow < 3) {
#pragma unroll
    for (int i = 0; i < 2; ++i) {
      int mt = wv * 2 + i;
#pragma unroll
      for (int r = 0; r < 4; ++r) {
        int pix = mt * 16 + lgrp * 4 + r;
        int oy = pix >> 5, ox = pix & 31;
        float val = tanhf(acc3[i][r] + bias3) * 0.1f;
        atomicAdd(&out[((size_t)(b * 3 + lrow) * 256 + (y0 + rb + oy)) * 256 +
                       (x0 + ox)],
                  val);
      }
    }
  }
}

extern "C" void kernel_launch(void* const* d_in, const int* in_sizes, int n_in,
                              void* d_out, int out_size, void* d_ws, size_t ws_size,
                              hipStream_t stream) {
  const float* x   = (const float*)d_in[0];
  const float* w1  = (const float*)d_in[1];
  const float* b1  = (const float*)d_in[2];
  const float* w2  = (const float*)d_in[3];
  const float* b2  = (const float*)d_in[4];
  const float* w3  = (const float*)d_in[5];
  const float* b3  = (const float*)d_in[6];
  const float* pw1 = (const float*)d_in[7];
  const float* pb1 = (const float*)d_in[8];
  const float* pw2 = (const float*)d_in[9];
  const float* pb2 = (const float*)d_in[10];
  float* out = (float*)d_out;

  float* feat = (float*)d_ws;                                  // 6144 floats
  int* posw = (int*)((char*)d_ws + 6144 * sizeof(float));      // 256 ints

  pool_kernel<<<1536, 256, 0, stream>>>(x, feat);
  mlp_kernel<<<BATCH, 128, 0, stream>>>(feat, pw1, pb1, pw2, pb2, posw);
  int n4 = (BATCH * CH * HH * WW) / 4;
  copy_kernel<<<(n4 + 255) / 256, 256, 0, stream>>>((const float4*)x, (float4*)out, n4);
  patch_kernel<<<BATCH * NPATCH * 8, 256, 0, stream>>>(x, w1, b1, w2, b2, w3, b3, posw, out);
}

// Round 5
// 47.955 us; speedup vs baseline: 3.1721x; 1.4126x over previous
//
#include <hip/hip_runtime.h>
#include <math.h>

#define BATCH 32
#define CH 3
#define HH 256
#define WW 256
#define PP 32
#define NPATCH 4

typedef __attribute__((ext_vector_type(8))) short short8;
typedef __attribute__((ext_vector_type(4))) float f32x4;

__device__ __forceinline__ unsigned short f2bf(float f) {
  union { float f; unsigned u; } cv;
  cv.f = f;
  unsigned u = cv.u;
  u += 0x7FFFu + ((u >> 16) & 1u);
  return (unsigned short)(u >> 16);
}

// ---------------- fused pool + copy (+ fragment pack in last block)
// blocks 0..383: b = blk/12, c = (blk%12)/4, q = blk%4 -> rows [q*64, q*64+64)
// block 384: pack bf16 MFMA weight-fragment tables into ws
__global__ __launch_bounds__(256) void pool_copy_kernel(
    const float* __restrict__ x, float* __restrict__ out,
    float* __restrict__ feat, const float* __restrict__ w1,
    const float* __restrict__ w2, const float* __restrict__ w3,
    unsigned short* __restrict__ w1f, unsigned short* __restrict__ w2f,
    unsigned short* __restrict__ w3f) {
  const int blk = blockIdx.x;
  const int t = threadIdx.x;
  if (blk == 384) {
    // w1f: [nt(2)][lane(64)][j(8)]  val = k<27 ? w1[(nt*16+lrow)*27+k] : 0, k=lgrp*8+j
    for (int idx = t; idx < 1024; idx += 256) {
      int nt = idx >> 9, lane = (idx >> 3) & 63, j = idx & 7;
      int lrow = lane & 15, lgrp = lane >> 4;
      int k = lgrp * 8 + j;
      float v = (k < 27) ? w1[(nt * 16 + lrow) * 27 + k] : 0.f;
      w1f[idx] = f2bf(v);
    }
    // w2f: [tap(9)][lane(64)][j(8)]  val = w2[lrow*288 + (lgrp*8+j)*9 + tap]
    for (int idx = t; idx < 4608; idx += 256) {
      int tap = idx >> 9, lane = (idx >> 3) & 63, j = idx & 7;
      int lrow = lane & 15, lgrp = lane >> 4;
      w2f[idx] = f2bf(w2[lrow * 288 + (lgrp * 8 + j) * 9 + tap]);
    }
    // w3f: [kk(5)][lane(64)][j(8)]  tap=2kk+(lgrp>>1), c2=(lgrp&1)*8+j
    for (int idx = t; idx < 2560; idx += 256) {
      int kk = idx >> 9, lane = (idx >> 3) & 63, j = idx & 7;
      int lrow = lane & 15, lgrp = lane >> 4;
      int tap = 2 * kk + (lgrp >> 1);
      int c2 = (lgrp & 1) * 8 + j;
      float v = (lrow < 3 && tap < 9) ? w3[lrow * 144 + c2 * 9 + tap] : 0.f;
      w3f[idx] = f2bf(v);
    }
    return;
  }

  const int b = blk / 12;
  const int rem = blk - b * 12;
  const int c = rem >> 2;
  const int q = rem & 3;
  const int rowl = t >> 2;          // 0..63
  const int colg = t & 3;           // 0..3 (64-col span)
  const int row = q * 64 + rowl;

  __shared__ float cellsum[16];
  if (t < 16) cellsum[t] = 0.f;
  __syncthreads();

  const size_t planeoff = ((size_t)(b * 3 + c) * 256 + row) * 64;  // in float4
  const float4* src = (const float4*)x + planeoff + colg * 16;
  float4* dst = (float4*)out + planeoff + colg * 16;
  float s0 = 0.f, s1 = 0.f;
#pragma unroll
  for (int k = 0; k < 8; ++k) {
    float4 v = src[k];
    dst[k] = v;
    s0 += v.x + v.y + v.z + v.w;
  }
#pragma unroll
  for (int k = 8; k < 16; ++k) {
    float4 v = src[k];
    dst[k] = v;
    s1 += v.x + v.y + v.z + v.w;
  }
  // reduce across the 16 lanes sharing colg within each wave
#pragma unroll
  for (int m = 4; m <= 32; m <<= 1) {
    s0 += __shfl_xor(s0, m, 64);
    s1 += __shfl_xor(s1, m, 64);
  }
  if ((t & 63) < 4) {
    int iloc = (t >> 6) >> 1;  // wave/2
    atomicAdd(&cellsum[iloc * 8 + colg * 2 + 0], s0);
    atomicAdd(&cellsum[iloc * 8 + colg * 2 + 1], s1);
  }
  __syncthreads();
  if (t < 16) {
    int iloc = t >> 3, j = t & 7;
    feat[b * 192 + c * 64 + (q * 2 + iloc) * 8 + j] = cellsum[t] * (1.f / 1024.f);
  }
}

// ---------------- mlp
__global__ __launch_bounds__(128) void mlp_kernel(const float* __restrict__ feat,
                                                  const float* __restrict__ pw1,
                                                  const float* __restrict__ pb1,
                                                  const float* __restrict__ pw2,
                                                  const float* __restrict__ pb2,
                                                  int* __restrict__ posw) {
  int b = blockIdx.x;
  int t = threadIdx.x;
  __shared__ float fs[192];
  __shared__ float hs[128];
  for (int k = t; k < 192; k += 128) fs[k] = feat[b * 192 + k];
  __syncthreads();
  float a = pb1[t];
  for (int k = 0; k < 192; ++k) a = fmaf(fs[k], pw1[t * 192 + k], a);
  hs[t] = fmaxf(a, 0.f);
  __syncthreads();
  if (t < 8) {
    float a2 = pb2[t];
    for (int k = 0; k < 128; ++k) a2 = fmaf(hs[k], pw2[t * 128 + k], a2);
    float sgm = 1.f / (1.f + expf(-a2));
    posw[b * 8 + t] = (int)floorf(sgm * (float)(HH - PP));
  }
}

// ---------------- patch (all-MFMA): per (b,p,s) block, 32x4 output rows
// frames: out 4x32 @ (y0+rb, x0); h2 6x34 @ (-1,-1); h1/xcol 8x36 @ (-2,-2); x 10x38 @ (-3,-3)
__global__ __launch_bounds__(256) void patch_kernel(
    const float* __restrict__ x, const float* __restrict__ b1,
    const float* __restrict__ b2, const float* __restrict__ b3,
    const unsigned short* __restrict__ w1f, const unsigned short* __restrict__ w2f,
    const unsigned short* __restrict__ w3f, const int* __restrict__ posw,
    float* __restrict__ out) {
  const int blk = blockIdx.x;
  const int s = blk & 7;
  const int p = (blk >> 3) & 3;
  const int b = blk >> 5;
  const int y0 = posw[b * 8 + p * 2 + 0];
  const int x0 = posw[b * 8 + p * 2 + 1];
  const int rb = s * 4;
  const int t = threadIdx.x;
  const int wv = t >> 6;
  const int lane = t & 63;
  const int lrow = lane & 15;   // MFMA A-row / B-col / D-col
  const int lgrp = lane >> 4;   // MFMA k-group; D-row = lgrp*4+reg

  __shared__ __align__(16) float xs[3][380];              // 4560 B
  __shared__ __align__(16) unsigned short buf[288 * 40];  // 23040 B: xcol then h1 (80B rows)
  __shared__ __align__(16) unsigned short h2ls[208 * 16]; // 6656 B

  // ---- stage x window (zero-padded)
#pragma unroll
  for (int k = 0; k < 5; ++k) {
    int idx = t + 256 * k;
    if (idx < 1140) {
      int c = idx / 380;
      int r = idx - c * 380;
      int ky = r / 38, kx = r - (r / 38) * 38;
      int gy = y0 + rb - 3 + ky, gx = x0 - 3 + kx;
      float v = 0.f;
      if ((unsigned)gy < 256u && (unsigned)gx < 256u)
        v = x[((size_t)(b * 3 + c) * 256 + gy) * 256 + gx];
      xs[c][r] = v;
    }
  }

  // frag loads (coalesced b128 from ws tables; latency hides under barriers)
  short8 b1f[2], b2f[9], b3f[5];
#pragma unroll
  for (int nt = 0; nt < 2; ++nt)
    b1f[nt] = *(const short8*)&w1f[(nt * 64 + lane) * 8];
#pragma unroll
  for (int tap = 0; tap < 9; ++tap)
    b2f[tap] = *(const short8*)&w2f[(tap * 64 + lane) * 8];
#pragma unroll
  for (int kk = 0; kk < 5; ++kk)
    b3f[kk] = *(const short8*)&w3f[(kk * 64 + lane) * 8];
  float b1v[2] = {b1[lrow], b1[16 + lrow]};
  float bias2 = b2[lrow];
  float bias3 = (lrow < 3) ? b3[lrow] : 0.f;

  __syncthreads();

  // ---- phase 1a: build xcol (im2col of xs) into buf: row pos, k = c*9+dy*3+dx (27, pad 32)
  auto xcoldo = [&](int pos) {
    int jy = pos / 36, jx = pos - (pos / 36) * 36;
    unsigned short cv[32];
#pragma unroll
    for (int c = 0; c < 3; ++c)
#pragma unroll
      for (int dy = 0; dy < 3; ++dy)
#pragma unroll
        for (int dx = 0; dx < 3; ++dx)
          cv[c * 9 + dy * 3 + dx] = f2bf(xs[c][(jy + dy) * 38 + (jx + dx)]);
#pragma unroll
    for (int k = 27; k < 32; ++k) cv[k] = 0;
#pragma unroll
    for (int qq = 0; qq < 4; ++qq) {
      short8 v8;
#pragma unroll
      for (int j = 0; j < 8; ++j) v8[j] = (short)cv[qq * 8 + j];
      *(short8*)&buf[pos * 40 + qq * 8] = v8;
    }
  };
  xcoldo(t);
  if (t < 32) xcoldo(256 + t);
  __syncthreads();

  // ---- phase 1b: h1 GEMM  M=288 (18 tiles), N=32 (2 tiles), K=32 (1 step)
  f32x4 acc1[5][2];
#pragma unroll
  for (int i = 0; i < 5; ++i) {
    int mt = wv + 4 * i;
    if (mt < 18) {
      short8 a = *(const short8*)&buf[(mt * 16 + lrow) * 40 + lgrp * 8];
      f32x4 z = f32x4{0.f, 0.f, 0.f, 0.f};
#pragma unroll
      for (int nt = 0; nt < 2; ++nt)
        acc1[i][nt] = __builtin_amdgcn_mfma_f32_16x16x32_bf16(a, b1f[nt], z, 0, 0, 0);
    }
  }
  __syncthreads();  // all xcol reads done before overwriting buf with h1

  // epilogue: bias+relu+mask -> buf[pos][c1] bf16
#pragma unroll
  for (int i = 0; i < 5; ++i) {
    int mt = wv + 4 * i;
    if (mt < 18) {
#pragma unroll
      for (int r = 0; r < 4; ++r) {
        int pos = mt * 16 + lgrp * 4 + r;
        int jy = pos / 36, jx = pos - (pos / 36) * 36;
        bool inim = ((unsigned)(y0 + rb - 2 + jy) < 256u) &&
                    ((unsigned)(x0 - 2 + jx) < 256u);
#pragma unroll
        for (int nt = 0; nt < 2; ++nt) {
          float v = fmaxf(acc1[i][nt][r] + b1v[nt], 0.f);
          buf[pos * 40 + nt * 16 + lrow] = inim ? f2bf(v) : (unsigned short)0;
        }
      }
    }
  }
  __syncthreads();

  // ---- phase 2: h2 GEMM, M=208 (13 tiles), K = 9 taps x 32 c1
  f32x4 acc[4];
#pragma unroll
  for (int i = 0; i < 4; ++i) {
    int mt = wv + 4 * i;
    if (mt < 13) {
      int pos = mt * 16 + lrow;
      int posc = pos < 204 ? pos : 203;
      int iy = posc / 34, ix = posc - (posc / 34) * 34;
      const unsigned short* abase = &buf[(iy * 36 + ix) * 40 + lgrp * 8];
      f32x4 c = f32x4{0.f, 0.f, 0.f, 0.f};
#pragma unroll
      for (int dy = 0; dy < 3; ++dy)
#pragma unroll
        for (int dx = 0; dx < 3; ++dx) {
          short8 a = *(const short8*)(abase + (dy * 36 + dx) * 40);
          c = __builtin_amdgcn_mfma_f32_16x16x32_bf16(a, b2f[dy * 3 + dx], c, 0, 0, 0);
        }
      acc[i] = c;
    } else {
      acc[i] = f32x4{0.f, 0.f, 0.f, 0.f};
    }
  }
#pragma unroll
  for (int i = 0; i < 4; ++i) {
    int mt = wv + 4 * i;
    if (mt < 13) {
#pragma unroll
      for (int r = 0; r < 4; ++r) {
        int pos = mt * 16 + lgrp * 4 + r;
        if (pos < 204) {
          int iy = pos / 34, ix = pos - (pos / 34) * 34;
          bool inim = ((unsigned)(y0 + rb - 1 + iy) < 256u) &&
                      ((unsigned)(x0 - 1 + ix) < 256u);
          float v = fmaxf(acc[i][r] + bias2, 0.f);
          h2ls[pos * 16 + lrow] = inim ? f2bf(v) : (unsigned short)0;
        }
      }
    }
  }
  __syncthreads();

  // ---- phase 3: h3 GEMM, M=128 (8 tiles), K=144 pad 160
  f32x4 acc3[2];
#pragma unroll
  for (int i = 0; i < 2; ++i) {
    int mt = wv * 2 + i;
    int pix = mt * 16 + lrow;
    int oy = pix >> 5, ox = pix & 31;
    f32x4 c = f32x4{0.f, 0.f, 0.f, 0.f};
#pragma unroll
    for (int kk = 0; kk < 5; ++kk) {
      int tap = 2 * kk + (lgrp >> 1);
      short8 a = short8{0, 0, 0, 0, 0, 0, 0, 0};
      if (tap < 9) {
        int dy = (tap * 11) >> 5;
        int dx = tap - dy * 3;
        a = *(const short8*)&h2ls[((oy + dy) * 34 + (ox + dx)) * 16 + (lgrp & 1) * 8];
      }
      c = __builtin_amdgcn_mfma_f32_16x16x32_bf16(a, b3f[kk], c, 0, 0, 0);
    }
    acc3[i] = c;
  }
  if (lrow < 3) {
#pragma unroll
    for (int i = 0; i < 2; ++i) {
      int mt = wv * 2 + i;
#pragma unroll
      for (int r = 0; r < 4; ++r) {
        int pix = mt * 16 + lgrp * 4 + r;
        int oy = pix >> 5, ox = pix & 31;
        float val = tanhf(acc3[i][r] + bias3) * 0.1f;
        atomicAdd(&out[((size_t)(b * 3 + lrow) * 256 + (y0 + rb + oy)) * 256 +
                       (x0 + ox)],
                  val);
      }
    }
  }
}

extern "C" void kernel_launch(void* const* d_in, const int* in_sizes, int n_in,
                              void* d_out, int out_size, void* d_ws, size_t ws_size,
                              hipStream_t stream) {
  const float* x   = (const float*)d_in[0];
  const float* w1  = (const float*)d_in[1];
  const float* b1  = (const float*)d_in[2];
  const float* w2  = (const float*)d_in[3];
  const float* b2  = (const float*)d_in[4];
  const float* w3  = (const float*)d_in[5];
  const float* b3  = (const float*)d_in[6];
  const float* pw1 = (const float*)d_in[7];
  const float* pb1 = (const float*)d_in[8];
  const float* pw2 = (const float*)d_in[9];
  const float* pb2 = (const float*)d_in[10];
  float* out = (float*)d_out;

  float* feat = (float*)d_ws;                                   // 6144 f
  int* posw = (int*)((char*)d_ws + 6144 * 4);                   // 256 i
  unsigned short* w1f = (unsigned short*)((char*)d_ws + 25600); // 1024 us
  unsigned short* w2f = (unsigned short*)((char*)d_ws + 27648); // 4608 us
  unsigned short* w3f = (unsigned short*)((char*)d_ws + 36864); // 2560 us

  pool_copy_kernel<<<385, 256, 0, stream>>>(x, out, feat, w1, w2, w3, w1f, w2f, w3f);
  mlp_kernel<<<BATCH, 128, 0, stream>>>(feat, pw1, pb1, pw2, pb2, posw);
  patch_kernel<<<BATCH * NPATCH * 8, 256, 0, stream>>>(x, b1, b2, b3, w1f, w2f, w3f,
                                                       posw, out);
}

// Round 7
// 47.372 us; speedup vs baseline: 3.2111x; 1.0123x over previous
//
#include <hip/hip_runtime.h>
#include <math.h>

#define BATCH 32
#define CH 3
#define HH 256
#define WW 256
#define PP 32
#define NPATCH 4

typedef __attribute__((ext_vector_type(8))) short short8;
typedef __attribute__((ext_vector_type(4))) float f32x4;

__device__ __forceinline__ unsigned short f2bf(float f) {
  union { float f; unsigned u; } cv;
  cv.f = f;
  unsigned u = cv.u;
  u += 0x7FFFu + ((u >> 16) & 1u);
  return (unsigned short)(u >> 16);
}

// ================= K1: fused copy + band-pool (+ weight pack) =================
// blocks 0..767: band (b,c,i) = 32 rows x 256 cols; copy x->out and produce
//                feat[b,c,i,0..7] entirely in-block (no cross-block reduce).
// blocks 768..775: pack bf16 MFMA weight-fragment tables + pw1T into ws.
__global__ __launch_bounds__(256) void prep_kernel(
    const float* __restrict__ x, float* __restrict__ out,
    float* __restrict__ feat, const float* __restrict__ w1,
    const float* __restrict__ w2, const float* __restrict__ w3,
    const float* __restrict__ pw1, unsigned short* __restrict__ w1f,
    unsigned short* __restrict__ w2f, unsigned short* __restrict__ w3f,
    float* __restrict__ pw1t) {
  const int blk = blockIdx.x;
  const int t = threadIdx.x;

  if (blk >= 768) {
    const int seg = blk - 768;
#pragma unroll
    for (int q = 0; q < 16; ++q) {
      int idx = seg * 4096 + q * 256 + t;  // 0..32767
      if (idx < 1024) {
        int nt = idx >> 9, lane_ = (idx >> 3) & 63, j = idx & 7;
        int lrow_ = lane_ & 15, lgrp_ = lane_ >> 4;
        int k = lgrp_ * 8 + j;
        w1f[idx] = f2bf(k < 27 ? w1[(nt * 16 + lrow_) * 27 + k] : 0.f);
      } else if (idx < 5632) {
        int id2 = idx - 1024;
        int tap = id2 >> 9, lane_ = (id2 >> 3) & 63, j = id2 & 7;
        int lrow_ = lane_ & 15, lgrp_ = lane_ >> 4;
        w2f[id2] = f2bf(w2[lrow_ * 288 + (lgrp_ * 8 + j) * 9 + tap]);
      } else if (idx < 8192) {
        int id3 = idx - 5632;
        int kk = id3 >> 9, lane_ = (id3 >> 3) & 63, j = id3 & 7;
        int lrow_ = lane_ & 15, lgrp_ = lane_ >> 4;
        int tap = 2 * kk + (lgrp_ >> 1);
        int c2 = (lgrp_ & 1) * 8 + j;
        float v = (lrow_ < 3 && tap < 9) ? w3[lrow_ * 144 + c2 * 9 + tap] : 0.f;
        w3f[id3] = f2bf(v);
      } else {
        int id4 = idx - 8192;              // 0..24575
        int k = id4 >> 7, tt = id4 & 127;  // pw1t[k][tt] = pw1[tt][k]
        pw1t[k * 128 + tt] = pw1[tt * 192 + k];
      }
    }
    return;
  }

  // band block
  const int b = blk / 24;
  const int rem = blk - b * 24;
  const int c = rem >> 3;
  const int i = rem & 7;
  const int wv = t >> 6;
  const int lane = t & 63;  // = float4 column index 0..63
  const int j = lane >> 3;  // pool cell column

  __shared__ float part[32];

  const size_t base4 = ((size_t)((b * 3 + c) * 256 + i * 32)) * 64;
  float s = 0.f;
#pragma unroll
  for (int k = 0; k < 8; ++k) {
    int r = k * 4 + wv;  // band row 0..31
    size_t F = base4 + (size_t)r * 64 + lane;
    float4 v = ((const float4*)x)[F];
    ((float4*)out)[F] = v;
    s += v.x + v.y + v.z + v.w;
  }
  // reduce across the 8 lanes sharing j
  s += __shfl_xor(s, 1, 64);
  s += __shfl_xor(s, 2, 64);
  s += __shfl_xor(s, 4, 64);
  if ((lane & 7) == 0) part[wv * 8 + j] = s;
  __syncthreads();
  if (t < 8) {
    float tot = part[t] + part[8 + t] + part[16 + t] + part[24 + t];
    feat[b * 192 + c * 64 + i * 8 + t] = tot * (1.f / 1024.f);
  }
}

// ================= K2: fused MLP + MFMA patch pipeline =================
// per (b,p,s) block, 32x4 output rows; MLP recomputed per block (bitwise
// identical across blocks of the same b -> consistent positions).
__global__ __launch_bounds__(256) void patch_kernel(
    const float* __restrict__ x, float* __restrict__ out,
    const float* __restrict__ b1, const float* __restrict__ b2,
    const float* __restrict__ b3, const float* __restrict__ pb1,
    const float* __restrict__ pw2, const float* __restrict__ pb2,
    const float* __restrict__ feat, const float* __restrict__ pw1t,
    const unsigned short* __restrict__ w1f, const unsigned short* __restrict__ w2f,
    const unsigned short* __restrict__ w3f) {
  const int blk = blockIdx.x;
  const int s = blk & 7;
  const int p = (blk >> 3) & 3;
  const int b = blk >> 5;
  const int rb = s * 4;
  const int t = threadIdx.x;
  const int wv = t >> 6;
  const int lane = t & 63;
  const int lrow = lane & 15;   // MFMA A-row / B-col / D-col
  const int lgrp = lane >> 4;   // MFMA k-group; D-row = lgrp*4+reg

  __shared__ __align__(16) float xs[3][380];              // 4560 B (MLP aliases)
  __shared__ __align__(16) unsigned short buf[288 * 40];  // 23040 B
  __shared__ __align__(16) unsigned short h2ls[208 * 16]; // 6656 B
  __shared__ int pos_sh[2];

  // fragment loads early (independent; latency hides under MLP)
  short8 b1f[2], b2f[9], b3f[5];
#pragma unroll
  for (int nt = 0; nt < 2; ++nt)
    b1f[nt] = *(const short8*)&w1f[(nt * 64 + lane) * 8];
#pragma unroll
  for (int tap = 0; tap < 9; ++tap)
    b2f[tap] = *(const short8*)&w2f[(tap * 64 + lane) * 8];
#pragma unroll
  for (int kk = 0; kk < 5; ++kk)
    b3f[kk] = *(const short8*)&w3f[(kk * 64 + lane) * 8];
  float b1v[2] = {b1[lrow], b1[16 + lrow]};
  float bias2 = b2[lrow];
  float bias3 = (lrow < 3) ? b3[lrow] : 0.f;

  // ---- MLP (aliased into xs)
  float* fsL = &xs[0][0];   // 192 floats
  float* hsL = fsL + 192;   // 128 floats
  if (t < 192) fsL[t] = feat[b * 192 + t];
  __syncthreads();
  if (t < 128) {
    float a = pb1[t];
#pragma unroll 8
    for (int k = 0; k < 192; ++k) a = fmaf(fsL[k], pw1t[k * 128 + t], a);
    hsL[t] = fmaxf(a, 0.f);
  }
  __syncthreads();
  if (wv < 2) {
    int jj = p * 2 + wv;
    float a = hsL[lane] * pw2[jj * 128 + lane] +
              hsL[64 + lane] * pw2[jj * 128 + 64 + lane];
#pragma unroll
    for (int m = 1; m <= 32; m <<= 1) a += __shfl_xor(a, m, 64);
    if (lane == 0) {
      float a2 = a + pb2[jj];
      float sgm = 1.f / (1.f + expf(-a2));
      pos_sh[wv] = (int)floorf(sgm * (float)(HH - PP));
    }
  }
  __syncthreads();
  const int y0 = pos_sh[0];
  const int x0 = pos_sh[1];
  __syncthreads();  // all reads of fsL/hsL + pos done before xs overwrite

  // ---- stage x window (zero-padded)
#pragma unroll
  for (int k = 0; k < 5; ++k) {
    int idx = t + 256 * k;
    if (idx < 1140) {
      int c = idx / 380;
      int r = idx - c * 380;
      int ky = r / 38, kx = r - (r / 38) * 38;
      int gy = y0 + rb - 3 + ky, gx = x0 - 3 + kx;
      float v = 0.f;
      if ((unsigned)gy < 256u && (unsigned)gx < 256u)
        v = x[((size_t)(b * 3 + c) * 256 + gy) * 256 + gx];
      xs[c][r] = v;
    }
  }
  __syncthreads();

  // ---- im2col of xs -> buf (row=pos, k=c*9+dy*3+dx, 27 pad 32)
  auto xcoldo = [&](int pos) {
    int jy = pos / 36, jx = pos - (pos / 36) * 36;
    unsigned short cv[32];
#pragma unroll
    for (int c = 0; c < 3; ++c)
#pragma unroll
      for (int dy = 0; dy < 3; ++dy)
#pragma unroll
        for (int dx = 0; dx < 3; ++dx)
          cv[c * 9 + dy * 3 + dx] = f2bf(xs[c][(jy + dy) * 38 + (jx + dx)]);
#pragma unroll
    for (int k = 27; k < 32; ++k) cv[k] = 0;
#pragma unroll
    for (int qq = 0; qq < 4; ++qq) {
      short8 v8;
#pragma unroll
      for (int j = 0; j < 8; ++j) v8[j] = (short)cv[qq * 8 + j];
      *(short8*)&buf[pos * 40 + qq * 8] = v8;
    }
  };
  xcoldo(t);
  if (t < 32) xcoldo(256 + t);
  __syncthreads();

  // ---- h1 GEMM  M=288 (18 tiles), N=32, K=32
  f32x4 acc1[5][2];
#pragma unroll
  for (int i = 0; i < 5; ++i) {
    int mt = wv + 4 * i;
    if (mt < 18) {
      short8 a = *(const short8*)&buf[(mt * 16 + lrow) * 40 + lgrp * 8];
      f32x4 z = f32x4{0.f, 0.f, 0.f, 0.f};
#pragma unroll
      for (int nt = 0; nt < 2; ++nt)
        acc1[i][nt] = __builtin_amdgcn_mfma_f32_16x16x32_bf16(a, b1f[nt], z, 0, 0, 0);
    }
  }
  __syncthreads();  // xcol reads done before overwriting buf with h1

  // epilogue: bias+relu+mask -> buf[pos][c1] bf16
#pragma unroll
  for (int i = 0; i < 5; ++i) {
    int mt = wv + 4 * i;
    if (mt < 18) {
#pragma unroll
      for (int r = 0; r < 4; ++r) {
        int pos = mt * 16 + lgrp * 4 + r;
        int jy = pos / 36, jx = pos - (pos / 36) * 36;
        bool inim = ((unsigned)(y0 + rb - 2 + jy) < 256u) &&
                    ((unsigned)(x0 - 2 + jx) < 256u);
#pragma unroll
        for (int nt = 0; nt < 2; ++nt) {
          float v = fmaxf(acc1[i][nt][r] + b1v[nt], 0.f);
          buf[pos * 40 + nt * 16 + lrow] = inim ? f2bf(v) : (unsigned short)0;
        }
      }
    }
  }
  __syncthreads();

  // ---- h2 GEMM, M=208 (13 tiles), K = 9 taps x 32 c1
  f32x4 acc[4];
#pragma unroll
  for (int i = 0; i < 4; ++i) {
    int mt = wv + 4 * i;
    if (mt < 13) {
      int pos = mt * 16 + lrow;
      int posc = pos < 204 ? pos : 203;
      int iy = posc / 34, ix = posc - (posc / 34) * 34;
      const unsigned short* abase = &buf[(iy * 36 + ix) * 40 + lgrp * 8];
      f32x4 c = f32x4{0.f, 0.f, 0.f, 0.f};
#pragma unroll
      for (int dy = 0; dy < 3; ++dy)
#pragma unroll
        for (int dx = 0; dx < 3; ++dx) {
          short8 a = *(const short8*)(abase + (dy * 36 + dx) * 40);
          c = __builtin_amdgcn_mfma_f32_16x16x32_bf16(a, b2f[dy * 3 + dx], c, 0, 0, 0);
        }
      acc[i] = c;
    } else {
      acc[i] = f32x4{0.f, 0.f, 0.f, 0.f};
    }
  }
#pragma unroll
  for (int i = 0; i < 4; ++i) {
    int mt = wv + 4 * i;
    if (mt < 13) {
#pragma unroll
      for (int r = 0; r < 4; ++r) {
        int pos = mt * 16 + lgrp * 4 + r;
        if (pos < 204) {
          int iy = pos / 34, ix = pos - (pos / 34) * 34;
          bool inim = ((unsigned)(y0 + rb - 1 + iy) < 256u) &&
                      ((unsigned)(x0 - 1 + ix) < 256u);
          float v = fmaxf(acc[i][r] + bias2, 0.f);
          h2ls[pos * 16 + lrow] = inim ? f2bf(v) : (unsigned short)0;
        }
      }
    }
  }
  __syncthreads();

  // ---- h3 GEMM, M=128 (8 tiles), K=144 pad 160
  f32x4 acc3[2];
#pragma unroll
  for (int i = 0; i < 2; ++i) {
    int mt = wv * 2 + i;
    int pix = mt * 16 + lrow;
    int oy = pix >> 5, ox = pix & 31;
    f32x4 c = f32x4{0.f, 0.f, 0.f, 0.f};
#pragma unroll
    for (int kk = 0; kk < 5; ++kk) {
      int tap = 2 * kk + (lgrp >> 1);
      short8 a = short8{0, 0, 0, 0, 0, 0, 0, 0};
      if (tap < 9) {
        int dy = (tap * 11) >> 5;
        int dx = tap - dy * 3;
        a = *(const short8*)&h2ls[((oy + dy) * 34 + (ox + dx)) * 16 + (lgrp & 1) * 8];
      }
      c = __builtin_amdgcn_mfma_f32_16x16x32_bf16(a, b3f[kk], c, 0, 0, 0);
    }
    acc3[i] = c;
  }
  if (lrow < 3) {
#pragma unroll
    for (int i = 0; i < 2; ++i) {
      int mt = wv * 2 + i;
#pragma unroll
      for (int r = 0; r < 4; ++r) {
        int pix = mt * 16 + lgrp * 4 + r;
        int oy = pix >> 5, ox = pix & 31;
        float val = tanhf(acc3[i][r] + bias3) * 0.1f;
        atomicAdd(&out[((size_t)(b * 3 + lrow) * 256 + (y0 + rb + oy)) * 256 +
                       (x0 + ox)],
                  val);
      }
    }
  }
}

extern "C" void kernel_launch(void* const* d_in, const int* in_sizes, int n_in,
                              void* d_out, int out_size, void* d_ws, size_t ws_size,
                              hipStream_t stream) {
  const float* x   = (const float*)d_in[0];
  const float* w1  = (const float*)d_in[1];
  const float* b1  = (const float*)d_in[2];
  const float* w2  = (const float*)d_in[3];
  const float* b2  = (const float*)d_in[4];
  const float* w3  = (const float*)d_in[5];
  const float* b3  = (const float*)d_in[6];
  const float* pw1 = (const float*)d_in[7];
  const float* pb1 = (const float*)d_in[8];
  const float* pw2 = (const float*)d_in[9];
  const float* pb2 = (const float*)d_in[10];
  float* out = (float*)d_out;

  // ws layout (total ~136 KB)
  float* feat = (float*)d_ws;                                    // 6144 f  @0
  unsigned short* w1f = (unsigned short*)((char*)d_ws + 24576);  // 1024 us
  unsigned short* w2f = (unsigned short*)((char*)d_ws + 26624);  // 4608 us
  unsigned short* w3f = (unsigned short*)((char*)d_ws + 35840);  // 2560 us
  float* pw1t = (float*)((char*)d_ws + 40960);                   // 24576 f

  prep_kernel<<<776, 256, 0, stream>>>(x, out, feat, w1, w2, w3, pw1,
                                       w1f, w2f, w3f, pw1t);
  patch_kernel<<<BATCH * NPATCH * 8, 256, 0, stream>>>(
      x, out, b1, b2, b3, pb1, pw2, pb2, feat, pw1t, w1f, w2f, w3f);
}